// Round 2
// baseline (871.815 us; speedup 1.0000x reference)
//
#include <hip/hip_runtime.h>
#include <hip/hip_bf16.h>

#define cN0 500000
#define cN1 100000
#define cN2 25000
#define cE0 1600000
#define cE1 400000

typedef __bf16 bf16x8 __attribute__((ext_vector_type(8)));
typedef __bf16 bf16x4 __attribute__((ext_vector_type(4)));
typedef float f32x4 __attribute__((ext_vector_type(4)));

// ---------------- CSR build (both hops fused per stage) ----------------

__global__ void k_hist(const int* __restrict__ d0, const int* __restrict__ d1,
                       int* __restrict__ c0, int* __restrict__ c1) {
    int i = blockIdx.x * blockDim.x + threadIdx.x;
    if (i < cE0) {
        atomicAdd(&c0[d0[i]], 1);
    } else {
        int j = i - cE0;
        if (j < cE1) atomicAdd(&c1[d1[j]], 1);
    }
}

// blocks [0,nb0) -> a0 (len cN1, bsum[0..]); blocks [nb0,nb0+nb1) -> a1 (len cN2, bsum[128..])
__global__ void k_scan1(int* __restrict__ a0, int* __restrict__ a1, int nb0,
                        int* __restrict__ bsum) {
    __shared__ int lds[256];
    const int t = threadIdx.x;
    int* a; int n; int* bs; int bb;
    if ((int)blockIdx.x < nb0) { a = a0; n = cN1; bs = bsum;       bb = blockIdx.x; }
    else                       { a = a1; n = cN2; bs = bsum + 128; bb = blockIdx.x - nb0; }
    const int base = bb * 1024 + t * 4;
    int v0 = (base + 0 < n) ? a[base + 0] : 0;
    int v1 = (base + 1 < n) ? a[base + 1] : 0;
    int v2 = (base + 2 < n) ? a[base + 2] : 0;
    int v3 = (base + 3 < n) ? a[base + 3] : 0;
    const int s = v0 + v1 + v2 + v3;
    lds[t] = s;
    __syncthreads();
    int x = s;
    for (int d = 1; d < 256; d <<= 1) {
        int y = (t >= d) ? lds[t - d] : 0;
        __syncthreads();
        x += y;
        lds[t] = x;
        __syncthreads();
    }
    if (t == 255) bs[bb] = x;
    int e0 = x - s;
    int e1 = e0 + v0, e2 = e1 + v1, e3 = e2 + v2;
    if (base + 0 < n) a[base + 0] = e0;
    if (base + 1 < n) a[base + 1] = e1;
    if (base + 2 < n) a[base + 2] = e2;
    if (base + 3 < n) a[base + 3] = e3;
}

// block 0 -> bsum[0..nb0), block 1 -> bsum[128..128+nb1)
__global__ void k_scan2(int* __restrict__ bsum, int nb0, int nb1) {
    __shared__ int lds[128];
    const int t = threadIdx.x;
    int* bs = bsum + blockIdx.x * 128;
    const int nb = (blockIdx.x == 0) ? nb0 : nb1;
    int v = (t < nb) ? bs[t] : 0;
    lds[t] = v;
    __syncthreads();
    int x = v;
    for (int d = 1; d < 128; d <<= 1) {
        int y = (t >= d) ? lds[t - d] : 0;
        __syncthreads();
        x += y;
        lds[t] = x;
        __syncthreads();
    }
    if (t < nb) bs[t] = x - v;
}

// finalize offsets + seed cursors, both hops in one grid
__global__ void k_scan3(int* __restrict__ off0, int* __restrict__ off1,
                        const int* __restrict__ bsum,
                        int* __restrict__ cur0, int* __restrict__ cur1) {
    int i = blockIdx.x * blockDim.x + threadIdx.x;
    if (i < cN1) {
        int v = off0[i] + bsum[i >> 10];
        off0[i] = v;
        cur0[i] = v;
    }
    if (i < cN2) {
        int v = off1[i] + bsum[128 + (i >> 10)];
        off1[i] = v;
        cur1[i] = v;
    }
    if (i == 0) { off0[cN1] = cE0; off1[cN2] = cE1; }
}

__global__ void k_scatter(const int* __restrict__ e0s, const int* __restrict__ e0d,
                          const int* __restrict__ e1s, const int* __restrict__ e1d,
                          int* __restrict__ cur0, int* __restrict__ cur1,
                          int* __restrict__ srcs0, int* __restrict__ srcs1) {
    int i = blockIdx.x * blockDim.x + threadIdx.x;
    if (i < cE0) {
        int p = atomicAdd(&cur0[e0d[i]], 1);
        srcs0[p] = e0s[i];
    } else {
        int j = i - cE0;
        if (j < cE1) {
            int p = atomicAdd(&cur1[e1d[j]], 1);
            srcs1[p] = e1s[j];
        }
    }
}

// ---------------- weight concat (fp32 -> bf16), both layers ----------------
__global__ void k_wcat(const float* __restrict__ Wl0, const float* __restrict__ Wr0,
                       const float* __restrict__ Wl1, const float* __restrict__ Wr1,
                       __bf16* __restrict__ Wc0, __bf16* __restrict__ Wc1) {
    int i = blockIdx.x * blockDim.x + threadIdx.x;
    if (i < 256 * 256) {
        int j = i >> 8, k = i & 255;
        float v = (k < 128) ? Wl0[j * 128 + k] : Wr0[j * 128 + (k - 128)];
        Wc0[i] = (__bf16)v;
    } else {
        int i2 = i - 256 * 256;
        if (i2 < 128 * 512) {
            int j = i2 >> 9, k = i2 & 511;
            float v = (k < 256) ? Wl1[j * 256 + k] : Wr1[j * 256 + (k - 256)];
            Wc1[i2] = (__bf16)v;
        }
    }
}

// ---------------- x (fp32) -> xb (bf16) cast; also fills M0 right half ----------------
__global__ __launch_bounds__(256) void k_cast(const float* __restrict__ x,
                                              __bf16* __restrict__ xb,
                                              __bf16* __restrict__ M0) {
    const size_t t = (size_t)blockIdx.x * 256 + threadIdx.x;
    const size_t base = t * 8;                     // element index < 64M
    const f32x4 a = __builtin_nontemporal_load((const f32x4*)(x + base));
    const f32x4 b = __builtin_nontemporal_load((const f32x4*)(x + base + 4));
    bf16x8 o;
    o[0] = (__bf16)a[0]; o[1] = (__bf16)a[1]; o[2] = (__bf16)a[2]; o[3] = (__bf16)a[3];
    o[4] = (__bf16)b[0]; o[5] = (__bf16)b[1]; o[6] = (__bf16)b[2]; o[7] = (__bf16)b[3];
    *(bf16x8*)(xb + base) = o;
    const int row = (int)(base >> 7);
    if (row < cN1) {
        const int col = (int)(base & 127);
        *(bf16x8*)(M0 + (size_t)row * 256 + 128 + col) = o;
    }
}

// ---------------- hop0 aggregation: M0[g][0:128] = bf16(mean xb_src) ----------------
__global__ __launch_bounds__(256) void k_agg0(
    const __bf16* __restrict__ xb,
    const int* __restrict__ off, const int* __restrict__ srcs,
    __bf16* __restrict__ M0)
{
    const int tid = threadIdx.x;
    const int slot = tid >> 5;          // 0..7
    const int ln = tid & 31;            // dims ln*4 .. ln*4+3
    const int g = blockIdx.x * 8 + slot;
    if (g >= cN1) return;
    const int e0 = off[g], e1 = off[g + 1];
    float a0 = 0.f, a1 = 0.f, a2 = 0.f, a3 = 0.f;
    int e = e0;
    for (; e + 4 <= e1; e += 4) {
        const int s0 = srcs[e], s1 = srcs[e + 1], s2 = srcs[e + 2], s3 = srcs[e + 3];
        const bf16x4 r0 = *(const bf16x4*)(xb + (size_t)s0 * 128 + ln * 4);
        const bf16x4 r1 = *(const bf16x4*)(xb + (size_t)s1 * 128 + ln * 4);
        const bf16x4 r2 = *(const bf16x4*)(xb + (size_t)s2 * 128 + ln * 4);
        const bf16x4 r3 = *(const bf16x4*)(xb + (size_t)s3 * 128 + ln * 4);
        a0 += ((float)r0[0] + (float)r1[0]) + ((float)r2[0] + (float)r3[0]);
        a1 += ((float)r0[1] + (float)r1[1]) + ((float)r2[1] + (float)r3[1]);
        a2 += ((float)r0[2] + (float)r1[2]) + ((float)r2[2] + (float)r3[2]);
        a3 += ((float)r0[3] + (float)r1[3]) + ((float)r2[3] + (float)r3[3]);
    }
    for (; e < e1; ++e) {
        const int s = srcs[e];
        const bf16x4 r = *(const bf16x4*)(xb + (size_t)s * 128 + ln * 4);
        a0 += (float)r[0]; a1 += (float)r[1]; a2 += (float)r[2]; a3 += (float)r[3];
    }
    const int cnt = e1 - e0;
    const float inv = 1.f / (float)(cnt > 0 ? cnt : 1);
    bf16x4 oa;
    oa[0] = (__bf16)(a0 * inv); oa[1] = (__bf16)(a1 * inv);
    oa[2] = (__bf16)(a2 * inv); oa[3] = (__bf16)(a3 * inv);
    *(bf16x4*)(M0 + (size_t)g * 256 + ln * 4) = oa;
}

// ---------------- hop1 aggregation: M1[g] = [bf16(mean h_src) | h[g]] ----------------
__global__ __launch_bounds__(256) void k_agg1(
    const __bf16* __restrict__ h,
    const int* __restrict__ off, const int* __restrict__ srcs,
    __bf16* __restrict__ M1)
{
    const int tid = threadIdx.x;
    const int wave = tid >> 6;
    const int lane = tid & 63;          // dims lane*4 .. +3
    const int g = blockIdx.x * 4 + wave;
    if (g >= cN2) return;
    const int e0 = off[g], e1 = off[g + 1];
    float a0 = 0.f, a1 = 0.f, a2 = 0.f, a3 = 0.f;
    int e = e0;
    for (; e + 4 <= e1; e += 4) {
        const int s0 = srcs[e], s1 = srcs[e + 1], s2 = srcs[e + 2], s3 = srcs[e + 3];
        const bf16x4 r0 = *(const bf16x4*)(h + (size_t)s0 * 256 + lane * 4);
        const bf16x4 r1 = *(const bf16x4*)(h + (size_t)s1 * 256 + lane * 4);
        const bf16x4 r2 = *(const bf16x4*)(h + (size_t)s2 * 256 + lane * 4);
        const bf16x4 r3 = *(const bf16x4*)(h + (size_t)s3 * 256 + lane * 4);
        a0 += (float)r0[0] + (float)r1[0] + (float)r2[0] + (float)r3[0];
        a1 += (float)r0[1] + (float)r1[1] + (float)r2[1] + (float)r3[1];
        a2 += (float)r0[2] + (float)r1[2] + (float)r2[2] + (float)r3[2];
        a3 += (float)r0[3] + (float)r1[3] + (float)r2[3] + (float)r3[3];
    }
    for (; e < e1; ++e) {
        const int s = srcs[e];
        const bf16x4 r = *(const bf16x4*)(h + (size_t)s * 256 + lane * 4);
        a0 += (float)r[0]; a1 += (float)r[1]; a2 += (float)r[2]; a3 += (float)r[3];
    }
    const int cnt = e1 - e0;
    const float inv = 1.f / (float)(cnt > 0 ? cnt : 1);
    bf16x4 oa;
    oa[0] = (__bf16)(a0 * inv); oa[1] = (__bf16)(a1 * inv);
    oa[2] = (__bf16)(a2 * inv); oa[3] = (__bf16)(a3 * inv);
    *(bf16x4*)(M1 + (size_t)g * 512 + lane * 4) = oa;
    *(bf16x4*)(M1 + (size_t)g * 512 + 256 + lane * 4) =
        *(const bf16x4*)(h + (size_t)g * 256 + lane * 4);
}

// ---------------- bf16 MFMA GEMM: C = act(Mm[Mrows x K] @ W[N x K]^T + bias) ----------------
// block = 4 waves (2x2), tile 128(M) x (NJ*32)(N); wave = 64 x NJ*16 via 4xNJ of 16x16x32 MFMA.
// NJ=8 -> block tile 128x256 (full N in one pass: A read once). NJ=4 -> 128x128.
template<int K, int LDC, int NJ, int UNR, bool RELU, bool OUTBF16>
__global__ __launch_bounds__(256) void k_gemm(
    const __bf16* __restrict__ Mm, const __bf16* __restrict__ W,
    const float* __restrict__ bias,
    float* __restrict__ outf, __bf16* __restrict__ outb, int Mrows)
{
    const int tid = threadIdx.x;
    const int l = tid & 63;
    const int w = tid >> 6;
    const int wm = w & 1, wn = w >> 1;
    const int row0 = blockIdx.x * 128 + wm * 64;
    const int col0 = blockIdx.y * (NJ * 32) + wn * (NJ * 16);
    const int lr = l & 15;          // row (A) / col (B) within fragment
    const int lk = (l >> 4) * 8;    // k offset within fragment

    const __bf16* pa[4];
    const __bf16* pb[NJ];
    #pragma unroll
    for (int i = 0; i < 4; ++i) {
        int r = row0 + i * 16 + lr;
        r = (r < Mrows) ? r : (Mrows - 1);
        pa[i] = Mm + (size_t)r * K + lk;
    }
    #pragma unroll
    for (int j = 0; j < NJ; ++j)
        pb[j] = W + (size_t)(col0 + j * 16 + lr) * K + lk;

    f32x4 acc[4][NJ];
    #pragma unroll
    for (int i = 0; i < 4; ++i)
        #pragma unroll
        for (int j = 0; j < NJ; ++j)
            acc[i][j] = (f32x4)0.0f;

    #pragma unroll UNR
    for (int k0 = 0; k0 < K; k0 += 32) {
        bf16x8 fa[4], fb[NJ];
        #pragma unroll
        for (int i = 0; i < 4; ++i) fa[i] = *(const bf16x8*)(pa[i] + k0);
        #pragma unroll
        for (int j = 0; j < NJ; ++j) fb[j] = *(const bf16x8*)(pb[j] + k0);
        #pragma unroll
        for (int i = 0; i < 4; ++i)
            #pragma unroll
            for (int j = 0; j < NJ; ++j)
                acc[i][j] = __builtin_amdgcn_mfma_f32_16x16x32_bf16(fa[i], fb[j], acc[i][j], 0, 0, 0);
    }

    // C/D layout: col = lane&15, row = (lane>>4)*4 + reg  [m89/m91-verified]
    #pragma unroll
    for (int j = 0; j < NJ; ++j) {
        const int colg = col0 + j * 16 + lr;
        const float bj = bias[colg];
        #pragma unroll
        for (int i = 0; i < 4; ++i) {
            #pragma unroll
            for (int reg = 0; reg < 4; ++reg) {
                const int rowg = row0 + i * 16 + (l >> 4) * 4 + reg;
                if (rowg < Mrows) {
                    float v = acc[i][j][reg] + bj;
                    if (RELU) v = fmaxf(v, 0.f);
                    if (OUTBF16) outb[(size_t)rowg * LDC + colg] = (__bf16)v;
                    else         outf[(size_t)rowg * LDC + colg] = v;
                }
            }
        }
    }
}

// ---------------- launch ----------------

extern "C" void kernel_launch(void* const* d_in, const int* in_sizes, int n_in,
                              void* d_out, int out_size, void* d_ws, size_t ws_size,
                              hipStream_t stream) {
    const float* x   = (const float*)d_in[0];
    const float* Wl0 = (const float*)d_in[1];
    const float* bl0 = (const float*)d_in[2];
    const float* Wr0 = (const float*)d_in[3];
    const float* Wl1 = (const float*)d_in[4];
    const float* bl1 = (const float*)d_in[5];
    const float* Wr1 = (const float*)d_in[6];
    const int* e0s = (const int*)d_in[7];
    const int* e0d = (const int*)d_in[8];
    const int* e1s = (const int*)d_in[9];
    const int* e1d = (const int*)d_in[10];
    float* out = (float*)d_out;

    char* ws = (char*)d_ws;
    size_t pos = 0;
    auto alloc = [&](size_t nb) -> void* {
        void* p = ws + pos;
        pos += (nb + 255) & ~(size_t)255;
        return p;
    };
    // xb [500K x 128] bf16 (128MB); h [100K x 256] bf16 aliases xb (xb dead after agg0)
    __bf16* xb   = (__bf16*)alloc((size_t)cN0 * 128 * 2);
    __bf16* h    = xb;
    // M0 [100K x 256] bf16 (51.2MB); M1 [25K x 512] bf16 aliases M0 (M0 dead after gemm0)
    __bf16* M0   = (__bf16*)alloc((size_t)cN1 * 256 * 2);
    __bf16* M1   = M0;
    // off0 and off1 contiguous -> single memset
    int* off0    = (int*)alloc((size_t)(cN1 + 1 + cN2 + 1) * 4);
    int* off1    = off0 + (cN1 + 1);
    int* cur0    = (int*)alloc((size_t)cN1 * 4);
    int* cur1    = (int*)alloc((size_t)cN2 * 4);
    int* srcs0   = (int*)alloc((size_t)cE0 * 4);
    int* srcs1   = (int*)alloc((size_t)cE1 * 4);
    int* bsum    = (int*)alloc(256 * 4);            // [0..128) hop0, [128..256) hop1
    __bf16* Wc0  = (__bf16*)alloc(256 * 256 * 2);
    __bf16* Wc1  = (__bf16*)alloc(128 * 512 * 2);
    (void)ws_size; (void)in_sizes; (void)n_in; (void)out_size;

    const int nb0 = (cN1 + 1023) / 1024;   // 98
    const int nb1 = (cN2 + 1023) / 1024;   // 25

    // --- CSR build (both hops per launch) ---
    hipMemsetAsync(off0, 0, (size_t)(cN1 + 1 + cN2 + 1) * 4, stream);
    k_hist<<<(cE0 + cE1 + 255) / 256, 256, 0, stream>>>(e0d, e1d, off0, off1);
    k_scan1<<<nb0 + nb1, 256, 0, stream>>>(off0, off1, nb0, bsum);
    k_scan2<<<2, 128, 0, stream>>>(bsum, nb0, nb1);
    k_scan3<<<(cN1 + 255) / 256, 256, 0, stream>>>(off0, off1, bsum, cur0, cur1);
    k_scatter<<<(cE0 + cE1 + 255) / 256, 256, 0, stream>>>(e0s, e0d, e1s, e1d,
                                                           cur0, cur1, srcs0, srcs1);

    // --- weights to bf16 concat (both layers) ---
    k_wcat<<<(256 * 256 + 128 * 512 + 255) / 256, 256, 0, stream>>>(Wl0, Wr0, Wl1, Wr1, Wc0, Wc1);

    // --- x -> bf16 (also fills M0 right half); placed just before agg0 for L3 residency ---
    k_cast<<<(cN0 * 128 / 8) / 256, 256, 0, stream>>>(x, xb, M0);

    // --- hop 0 ---
    k_agg0<<<(cN1 + 7) / 8, 256, 0, stream>>>(xb, off0, srcs0, M0);
    {
        dim3 grid((cN1 + 127) / 128, 1);   // 128x256 tile: A read once
        k_gemm<256, 256, 8, 1, true, true><<<grid, 256, 0, stream>>>(M0, Wc0, bl0, nullptr, h, cN1);
    }
    // --- hop 1 ---
    k_agg1<<<(cN2 + 3) / 4, 256, 0, stream>>>(h, off1, srcs1, M1);
    {
        dim3 grid((cN2 + 127) / 128, 1);
        k_gemm<512, 128, 4, 2, false, false><<<grid, 256, 0, stream>>>(M1, Wc1, bl1, out, nullptr, cN2);
    }
}

// Round 5
// 745.855 us; speedup vs baseline: 1.1689x; 1.1689x over previous
//
#include <hip/hip_runtime.h>
#include <hip/hip_bf16.h>

#define cN0 500000
#define cN1 100000
#define cN2 25000
#define cE0 1600000
#define cE1 400000

typedef __bf16 bf16x8 __attribute__((ext_vector_type(8)));
typedef __bf16 bf16x4 __attribute__((ext_vector_type(4)));
typedef float f32x4 __attribute__((ext_vector_type(4)));

// ---------------- CSR build ----------------
// XCD-affine histogram: 4096 blocks; [0,2048) hop0, [2048,4096) hop1.
// slice = b&7 -> lands on XCD (b%8) via round-robin dispatch; each XCD's L2
// privately owns a 1/8 dst-range of the counter array (no cross-XCD line ping-pong).
__global__ void k_histx(const int* __restrict__ d0, const int* __restrict__ d1,
                        int* __restrict__ c0, int* __restrict__ c1) {
    int b = blockIdx.x;
    const int* d; int* c; int E, sz;
    if (b < 2048) { d = d0; c = c0; E = cE0; sz = 12500; }
    else          { b -= 2048; d = d1; c = c1; E = cE1; sz = 3125; }
    const int lo = (b & 7) * sz, hi = lo + sz;
    int i = (b >> 3) * 256 + threadIdx.x;
    for (; i < E; i += 65536) {
        const int dv = d[i];
        if (dv >= lo && dv < hi) atomicAdd(&c[dv], 1);
    }
}

// blocks [0,nb0) -> a0 (len cN1, bsum[0..]); blocks [nb0,nb0+nb1) -> a1 (len cN2, bsum[128..])
__global__ void k_scan1(int* __restrict__ a0, int* __restrict__ a1, int nb0,
                        int* __restrict__ bsum) {
    __shared__ int lds[256];
    const int t = threadIdx.x;
    int* a; int n; int* bs; int bb;
    if ((int)blockIdx.x < nb0) { a = a0; n = cN1; bs = bsum;       bb = blockIdx.x; }
    else                       { a = a1; n = cN2; bs = bsum + 128; bb = blockIdx.x - nb0; }
    const int base = bb * 1024 + t * 4;
    int v0 = (base + 0 < n) ? a[base + 0] : 0;
    int v1 = (base + 1 < n) ? a[base + 1] : 0;
    int v2 = (base + 2 < n) ? a[base + 2] : 0;
    int v3 = (base + 3 < n) ? a[base + 3] : 0;
    const int s = v0 + v1 + v2 + v3;
    lds[t] = s;
    __syncthreads();
    int x = s;
    for (int d = 1; d < 256; d <<= 1) {
        int y = (t >= d) ? lds[t - d] : 0;
        __syncthreads();
        x += y;
        lds[t] = x;
        __syncthreads();
    }
    if (t == 255) bs[bb] = x;
    int e0 = x - s;
    int e1 = e0 + v0, e2 = e1 + v1, e3 = e2 + v2;
    if (base + 0 < n) a[base + 0] = e0;
    if (base + 1 < n) a[base + 1] = e1;
    if (base + 2 < n) a[base + 2] = e2;
    if (base + 3 < n) a[base + 3] = e3;
}

// block 0 -> bsum[0..nb0), block 1 -> bsum[128..128+nb1)
__global__ void k_scan2(int* __restrict__ bsum, int nb0, int nb1) {
    __shared__ int lds[128];
    const int t = threadIdx.x;
    int* bs = bsum + blockIdx.x * 128;
    const int nb = (blockIdx.x == 0) ? nb0 : nb1;
    int v = (t < nb) ? bs[t] : 0;
    lds[t] = v;
    __syncthreads();
    int x = v;
    for (int d = 1; d < 128; d <<= 1) {
        int y = (t >= d) ? lds[t - d] : 0;
        __syncthreads();
        x += y;
        lds[t] = x;
        __syncthreads();
    }
    if (t < nb) bs[t] = x - v;
}

// finalize offsets + seed cursors, both hops in one grid
__global__ void k_scan3(int* __restrict__ off0, int* __restrict__ off1,
                        const int* __restrict__ bsum,
                        int* __restrict__ cur0, int* __restrict__ cur1) {
    int i = blockIdx.x * blockDim.x + threadIdx.x;
    if (i < cN1) {
        int v = off0[i] + bsum[i >> 10];
        off0[i] = v;
        cur0[i] = v;
    }
    if (i < cN2) {
        int v = off1[i] + bsum[128 + (i >> 10)];
        off1[i] = v;
        cur1[i] = v;
    }
    if (i == 0) { off0[cN1] = cE0; off1[cN2] = cE1; }
}

// XCD-affine scatter, same slicing as k_histx. Each XCD's L2 privately owns
// its cur/srcs slice (~0.85MB hop0), so the 4B scattered stores coalesce in L2
// instead of one 64B HBM writeback per store (round-2 counter: 127.5MB WRITE_SIZE).
__global__ void k_scatx(const int* __restrict__ s0, const int* __restrict__ d0,
                        const int* __restrict__ s1, const int* __restrict__ d1,
                        int* __restrict__ cur0, int* __restrict__ cur1,
                        int* __restrict__ o0, int* __restrict__ o1) {
    int b = blockIdx.x;
    const int *s, *d; int *cur, *o; int E, sz;
    if (b < 2048) { s = s0; d = d0; cur = cur0; o = o0; E = cE0; sz = 12500; }
    else          { b -= 2048; s = s1; d = d1; cur = cur1; o = o1; E = cE1; sz = 3125; }
    const int lo = (b & 7) * sz, hi = lo + sz;
    int i = (b >> 3) * 256 + threadIdx.x;
    for (; i < E; i += 65536) {
        const int dv = d[i];
        if (dv >= lo && dv < hi) {
            const int p = atomicAdd(&cur[dv], 1);
            o[p] = s[i];
        }
    }
}

// ---------------- weight concat (fp32 -> bf16), both layers ----------------
__global__ void k_wcat(const float* __restrict__ Wl0, const float* __restrict__ Wr0,
                       const float* __restrict__ Wl1, const float* __restrict__ Wr1,
                       __bf16* __restrict__ Wc0, __bf16* __restrict__ Wc1) {
    int i = blockIdx.x * blockDim.x + threadIdx.x;
    if (i < 256 * 256) {
        int j = i >> 8, k = i & 255;
        float v = (k < 128) ? Wl0[j * 128 + k] : Wr0[j * 128 + (k - 128)];
        Wc0[i] = (__bf16)v;
    } else {
        int i2 = i - 256 * 256;
        if (i2 < 128 * 512) {
            int j = i2 >> 9, k = i2 & 511;
            float v = (k < 256) ? Wl1[j * 256 + k] : Wr1[j * 256 + (k - 256)];
            Wc1[i2] = (__bf16)v;
        }
    }
}

// ---------------- x (fp32) -> xb (bf16) cast; also fills M0 right half ----------------
__global__ __launch_bounds__(256) void k_cast(const float* __restrict__ x,
                                              __bf16* __restrict__ xb,
                                              __bf16* __restrict__ M0) {
    const size_t t = (size_t)blockIdx.x * 256 + threadIdx.x;
    const size_t base = t * 8;                     // element index < 64M
    const f32x4 a = __builtin_nontemporal_load((const f32x4*)(x + base));
    const f32x4 b = __builtin_nontemporal_load((const f32x4*)(x + base + 4));
    bf16x8 o;
    o[0] = (__bf16)a[0]; o[1] = (__bf16)a[1]; o[2] = (__bf16)a[2]; o[3] = (__bf16)a[3];
    o[4] = (__bf16)b[0]; o[5] = (__bf16)b[1]; o[6] = (__bf16)b[2]; o[7] = (__bf16)b[3];
    *(bf16x8*)(xb + base) = o;
    const int row = (int)(base >> 7);
    if (row < cN1) {
        const int col = (int)(base & 127);
        *(bf16x8*)(M0 + (size_t)row * 256 + 128 + col) = o;
    }
}

// ---------------- hop0 aggregation: M0[g][0:128] = bf16(mean xb_src) ----------------
__global__ __launch_bounds__(256) void k_agg0(
    const __bf16* __restrict__ xb,
    const int* __restrict__ off, const int* __restrict__ srcs,
    __bf16* __restrict__ M0)
{
    const int tid = threadIdx.x;
    const int slot = tid >> 5;          // 0..7
    const int ln = tid & 31;            // dims ln*4 .. ln*4+3
    const int g = blockIdx.x * 8 + slot;
    if (g >= cN1) return;
    const int e0 = off[g], e1 = off[g + 1];
    float a0 = 0.f, a1 = 0.f, a2 = 0.f, a3 = 0.f;
    int e = e0;
    for (; e + 4 <= e1; e += 4) {
        const int s0 = srcs[e], s1 = srcs[e + 1], s2 = srcs[e + 2], s3 = srcs[e + 3];
        const bf16x4 r0 = *(const bf16x4*)(xb + (size_t)s0 * 128 + ln * 4);
        const bf16x4 r1 = *(const bf16x4*)(xb + (size_t)s1 * 128 + ln * 4);
        const bf16x4 r2 = *(const bf16x4*)(xb + (size_t)s2 * 128 + ln * 4);
        const bf16x4 r3 = *(const bf16x4*)(xb + (size_t)s3 * 128 + ln * 4);
        a0 += ((float)r0[0] + (float)r1[0]) + ((float)r2[0] + (float)r3[0]);
        a1 += ((float)r0[1] + (float)r1[1]) + ((float)r2[1] + (float)r3[1]);
        a2 += ((float)r0[2] + (float)r1[2]) + ((float)r2[2] + (float)r3[2]);
        a3 += ((float)r0[3] + (float)r1[3]) + ((float)r2[3] + (float)r3[3]);
    }
    for (; e < e1; ++e) {
        const int s = srcs[e];
        const bf16x4 r = *(const bf16x4*)(xb + (size_t)s * 128 + ln * 4);
        a0 += (float)r[0]; a1 += (float)r[1]; a2 += (float)r[2]; a3 += (float)r[3];
    }
    const int cnt = e1 - e0;
    const float inv = 1.f / (float)(cnt > 0 ? cnt : 1);
    bf16x4 oa;
    oa[0] = (__bf16)(a0 * inv); oa[1] = (__bf16)(a1 * inv);
    oa[2] = (__bf16)(a2 * inv); oa[3] = (__bf16)(a3 * inv);
    *(bf16x4*)(M0 + (size_t)g * 256 + ln * 4) = oa;
}

// ---------------- hop1 aggregation: M1[g] = [bf16(mean h_src) | h[g]] ----------------
__global__ __launch_bounds__(256) void k_agg1(
    const __bf16* __restrict__ h,
    const int* __restrict__ off, const int* __restrict__ srcs,
    __bf16* __restrict__ M1)
{
    const int tid = threadIdx.x;
    const int wave = tid >> 6;
    const int lane = tid & 63;          // dims lane*4 .. +3
    const int g = blockIdx.x * 4 + wave;
    if (g >= cN2) return;
    const int e0 = off[g], e1 = off[g + 1];
    float a0 = 0.f, a1 = 0.f, a2 = 0.f, a3 = 0.f;
    int e = e0;
    for (; e + 4 <= e1; e += 4) {
        const int s0 = srcs[e], s1 = srcs[e + 1], s2 = srcs[e + 2], s3 = srcs[e + 3];
        const bf16x4 r0 = *(const bf16x4*)(h + (size_t)s0 * 256 + lane * 4);
        const bf16x4 r1 = *(const bf16x4*)(h + (size_t)s1 * 256 + lane * 4);
        const bf16x4 r2 = *(const bf16x4*)(h + (size_t)s2 * 256 + lane * 4);
        const bf16x4 r3 = *(const bf16x4*)(h + (size_t)s3 * 256 + lane * 4);
        a0 += (float)r0[0] + (float)r1[0] + (float)r2[0] + (float)r3[0];
        a1 += (float)r0[1] + (float)r1[1] + (float)r2[1] + (float)r3[1];
        a2 += (float)r0[2] + (float)r1[2] + (float)r2[2] + (float)r3[2];
        a3 += (float)r0[3] + (float)r1[3] + (float)r2[3] + (float)r3[3];
    }
    for (; e < e1; ++e) {
        const int s = srcs[e];
        const bf16x4 r = *(const bf16x4*)(h + (size_t)s * 256 + lane * 4);
        a0 += (float)r[0]; a1 += (float)r[1]; a2 += (float)r[2]; a3 += (float)r[3];
    }
    const int cnt = e1 - e0;
    const float inv = 1.f / (float)(cnt > 0 ? cnt : 1);
    bf16x4 oa;
    oa[0] = (__bf16)(a0 * inv); oa[1] = (__bf16)(a1 * inv);
    oa[2] = (__bf16)(a2 * inv); oa[3] = (__bf16)(a3 * inv);
    *(bf16x4*)(M1 + (size_t)g * 512 + lane * 4) = oa;
    *(bf16x4*)(M1 + (size_t)g * 512 + 256 + lane * 4) =
        *(const bf16x4*)(h + (size_t)g * 256 + lane * 4);
}

// ---------------- bf16 MFMA GEMM: C = act(Mm[Mrows x K] @ W[N x K]^T + bias) ----------------
// block = 4 waves (2x2), tile 128(M) x (NJ*32)(N); NJ=4 proven config (~130 VGPR, no spill).
template<int K, int LDC, int NJ, int UNR, bool RELU, bool OUTBF16>
__global__ __launch_bounds__(256) void k_gemm(
    const __bf16* __restrict__ Mm, const __bf16* __restrict__ W,
    const float* __restrict__ bias,
    float* __restrict__ outf, __bf16* __restrict__ outb, int Mrows)
{
    const int tid = threadIdx.x;
    const int l = tid & 63;
    const int w = tid >> 6;
    const int wm = w & 1, wn = w >> 1;
    const int row0 = blockIdx.x * 128 + wm * 64;
    const int col0 = blockIdx.y * (NJ * 32) + wn * (NJ * 16);
    const int lr = l & 15;          // row (A) / col (B) within fragment
    const int lk = (l >> 4) * 8;    // k offset within fragment

    const __bf16* pa[4];
    const __bf16* pb[NJ];
    #pragma unroll
    for (int i = 0; i < 4; ++i) {
        int r = row0 + i * 16 + lr;
        r = (r < Mrows) ? r : (Mrows - 1);
        pa[i] = Mm + (size_t)r * K + lk;
    }
    #pragma unroll
    for (int j = 0; j < NJ; ++j)
        pb[j] = W + (size_t)(col0 + j * 16 + lr) * K + lk;

    f32x4 acc[4][NJ];
    #pragma unroll
    for (int i = 0; i < 4; ++i)
        #pragma unroll
        for (int j = 0; j < NJ; ++j)
            acc[i][j] = (f32x4)0.0f;

    #pragma unroll UNR
    for (int k0 = 0; k0 < K; k0 += 32) {
        bf16x8 fa[4], fb[NJ];
        #pragma unroll
        for (int i = 0; i < 4; ++i) fa[i] = *(const bf16x8*)(pa[i] + k0);
        #pragma unroll
        for (int j = 0; j < NJ; ++j) fb[j] = *(const bf16x8*)(pb[j] + k0);
        #pragma unroll
        for (int i = 0; i < 4; ++i)
            #pragma unroll
            for (int j = 0; j < NJ; ++j)
                acc[i][j] = __builtin_amdgcn_mfma_f32_16x16x32_bf16(fa[i], fb[j], acc[i][j], 0, 0, 0);
    }

    // C/D layout: col = lane&15, row = (lane>>4)*4 + reg  [m89/m91-verified]
    #pragma unroll
    for (int j = 0; j < NJ; ++j) {
        const int colg = col0 + j * 16 + lr;
        const float bj = bias[colg];
        #pragma unroll
        for (int i = 0; i < 4; ++i) {
            #pragma unroll
            for (int reg = 0; reg < 4; ++reg) {
                const int rowg = row0 + i * 16 + (l >> 4) * 4 + reg;
                if (rowg < Mrows) {
                    float v = acc[i][j][reg] + bj;
                    if (RELU) v = fmaxf(v, 0.f);
                    if (OUTBF16) outb[(size_t)rowg * LDC + colg] = (__bf16)v;
                    else         outf[(size_t)rowg * LDC + colg] = v;
                }
            }
        }
    }
}

// ---------------- launch ----------------

extern "C" void kernel_launch(void* const* d_in, const int* in_sizes, int n_in,
                              void* d_out, int out_size, void* d_ws, size_t ws_size,
                              hipStream_t stream) {
    const float* x   = (const float*)d_in[0];
    const float* Wl0 = (const float*)d_in[1];
    const float* bl0 = (const float*)d_in[2];
    const float* Wr0 = (const float*)d_in[3];
    const float* Wl1 = (const float*)d_in[4];
    const float* bl1 = (const float*)d_in[5];
    const float* Wr1 = (const float*)d_in[6];
    const int* e0s = (const int*)d_in[7];
    const int* e0d = (const int*)d_in[8];
    const int* e1s = (const int*)d_in[9];
    const int* e1d = (const int*)d_in[10];
    float* out = (float*)d_out;

    char* ws = (char*)d_ws;
    size_t pos = 0;
    auto alloc = [&](size_t nb) -> void* {
        void* p = ws + pos;
        pos += (nb + 255) & ~(size_t)255;
        return p;
    };
    // xb [500K x 128] bf16 (128MB); h [100K x 256] bf16 aliases xb (xb dead after agg0)
    __bf16* xb   = (__bf16*)alloc((size_t)cN0 * 128 * 2);
    __bf16* h    = xb;
    // M0 [100K x 256] bf16 (51.2MB); M1 [25K x 512] bf16 aliases M0 (M0 dead after gemm0)
    __bf16* M0   = (__bf16*)alloc((size_t)cN1 * 256 * 2);
    __bf16* M1   = M0;
    // off0 and off1 contiguous -> single memset
    int* off0    = (int*)alloc((size_t)(cN1 + 1 + cN2 + 1) * 4);
    int* off1    = off0 + (cN1 + 1);
    int* cur0    = (int*)alloc((size_t)cN1 * 4);
    int* cur1    = (int*)alloc((size_t)cN2 * 4);
    int* srcs0   = (int*)alloc((size_t)cE0 * 4);
    int* srcs1   = (int*)alloc((size_t)cE1 * 4);
    int* bsum    = (int*)alloc(256 * 4);            // [0..128) hop0, [128..256) hop1
    __bf16* Wc0  = (__bf16*)alloc(256 * 256 * 2);
    __bf16* Wc1  = (__bf16*)alloc(128 * 512 * 2);
    (void)ws_size; (void)in_sizes; (void)n_in; (void)out_size;

    const int nb0 = (cN1 + 1023) / 1024;   // 98
    const int nb1 = (cN2 + 1023) / 1024;   // 25

    // --- CSR build (XCD-affine hist + scatter, both hops per launch) ---
    hipMemsetAsync(off0, 0, (size_t)(cN1 + 1 + cN2 + 1) * 4, stream);
    k_histx<<<4096, 256, 0, stream>>>(e0d, e1d, off0, off1);
    k_scan1<<<nb0 + nb1, 256, 0, stream>>>(off0, off1, nb0, bsum);
    k_scan2<<<2, 128, 0, stream>>>(bsum, nb0, nb1);
    k_scan3<<<(cN1 + 255) / 256, 256, 0, stream>>>(off0, off1, bsum, cur0, cur1);
    k_scatx<<<4096, 256, 0, stream>>>(e0s, e0d, e1s, e1d, cur0, cur1, srcs0, srcs1);

    // --- weights to bf16 concat (both layers) ---
    k_wcat<<<(256 * 256 + 128 * 512 + 255) / 256, 256, 0, stream>>>(Wl0, Wr0, Wl1, Wr1, Wc0, Wc1);

    // --- x -> bf16 (also fills M0 right half); placed just before agg0 for L3 residency ---
    k_cast<<<(cN0 * 128 / 8) / 256, 256, 0, stream>>>(x, xb, M0);

    // --- hop 0 ---
    k_agg0<<<(cN1 + 7) / 8, 256, 0, stream>>>(xb, off0, srcs0, M0);
    {
        dim3 grid((cN1 + 127) / 128, 2);   // proven 128x128 config
        k_gemm<256, 256, 4, 2, true, true><<<grid, 256, 0, stream>>>(M0, Wc0, bl0, nullptr, h, cN1);
    }
    // --- hop 1 ---
    k_agg1<<<(cN2 + 3) / 4, 256, 0, stream>>>(h, off1, srcs1, M1);
    {
        dim3 grid((cN2 + 127) / 128, 1);
        k_gemm<512, 128, 4, 2, false, false><<<grid, 256, 0, stream>>>(M1, Wc1, bl1, out, nullptr, cN2);
    }
}